// Round 4
// baseline (51.156 us; speedup 1.0000x reference)
//
#include <hip/hip_runtime.h>

#define N_E   512
#define DIM   64
#define HW    4096        // 64*64
#define CHW   (64*HW)     // 262144
#define NPIX  131072      // 32*64*64

typedef __attribute__((ext_vector_type(8))) short  short8;   // 8 bf16 (4 VGPRs)
typedef __attribute__((ext_vector_type(4))) float  f32x4;

__device__ __forceinline__ unsigned short f2bf(float x) {
    unsigned u = __builtin_bit_cast(unsigned, x);
    return (unsigned short)((u + 0x7FFFu + ((u >> 16) & 1u)) >> 16);   // RNE
}

// --- prep: pack codebook into bf16 B-fragments + norms + zero loss slot ------
// frag[g], g = tile*128 + h*64 + lane : 8 bf16 = cb[tile*16+(lane&15)][h*32+(lane>>4)*8 + j]
__global__ __launch_bounds__(512) void vq_prep(
        const float* __restrict__ cb, float* __restrict__ cnh,
        uint4* __restrict__ frag, float* __restrict__ out) {
    int g    = blockIdx.x * 512 + threadIdx.x;   // 0..4095
    int tile = g >> 7;
    int h    = (g >> 6) & 1;
    int ln   = g & 63;
    const float* src = cb + (tile * 16 + (ln & 15)) * DIM + h * 32 + (ln >> 4) * 8;
    float4 a = *(const float4*)src;
    float4 b = *(const float4*)(src + 4);
    uint4 o;
    o.x = (unsigned)f2bf(a.x) | ((unsigned)f2bf(a.y) << 16);
    o.y = (unsigned)f2bf(a.z) | ((unsigned)f2bf(a.w) << 16);
    o.z = (unsigned)f2bf(b.x) | ((unsigned)f2bf(b.y) << 16);
    o.w = (unsigned)f2bf(b.z) | ((unsigned)f2bf(b.w) << 16);
    frag[g] = o;
    if (blockIdx.x == 0) {
        const float4* c = (const float4*)(cb + threadIdx.x * DIM);
        float s = 0.f;
        #pragma unroll
        for (int k = 0; k < DIM / 4; ++k) {
            float4 v = c[k];
            s += v.x * v.x + v.y * v.y + v.z * v.z + v.w * v.w;
        }
        cnh[threadIdx.x] = -0.5f * s;
        if (threadIdx.x == 0) out[0] = 0.f;
    }
}

// --- main: B streamed from L2 (no big LDS) -> 32 waves/CU --------------------
__global__ __launch_bounds__(512, 8) void vq_main(
        const float* __restrict__ z, const float* __restrict__ cb,
        const float* __restrict__ cnh, const uint4* __restrict__ frag,
        float* __restrict__ out) {
    __shared__ float cn[N_E];        // 2 KB
    __shared__ int   idx_lds[128];   // chosen code per pixel
    __shared__ float red[8];

    const int tid  = threadIdx.x;
    const int w    = tid >> 6;
    const int lane = tid & 63;
    const int col  = lane & 15;
    const int grp  = lane >> 4;

    cn[tid] = cnh[tid];

    const int pbase = blockIdx.x * 128;        // 128 pixels/block (16/wave)
    const int b     = pbase >> 12;
    const int hwp   = (pbase & 4095) + w * 16 + col;
    const float* zp = z + (size_t)b * CHW + hwp;   // + k*HW

    // z loads (fp32, kept for exact loss) — issued before the barrier
    float zf[2][8];
    #pragma unroll
    for (int h = 0; h < 2; ++h)
        #pragma unroll
        for (int j = 0; j < 8; ++j)
            zf[h][j] = zp[(h * 32 + grp * 8 + j) * HW];

    short8 afr[2];
    #pragma unroll
    for (int h = 0; h < 2; ++h)
        #pragma unroll
        for (int j = 0; j < 8; ++j)
            afr[h][j] = (short)f2bf(zf[h][j]);

    __syncthreads();

    // MFMA score loop: argmax of (z.c - 0.5||c||^2) == argmin distance
    float best[4];
    int   bid[4];
    #pragma unroll
    for (int r = 0; r < 4; ++r) { best[r] = -1e30f; bid[r] = 0; }

    const short8* B8 = (const short8*)frag;
    #pragma unroll 2
    for (int t = 0; t < 32; ++t) {
        short8 b0 = B8[t * 128 + lane];
        short8 b1 = B8[t * 128 + 64 + lane];
        const float c0 = cn[t * 16 + col];
        f32x4 acc = {c0, c0, c0, c0};
        acc = __builtin_amdgcn_mfma_f32_16x16x32_bf16(afr[0], b0, acc, 0, 0, 0);
        acc = __builtin_amdgcn_mfma_f32_16x16x32_bf16(afr[1], b1, acc, 0, 0, 0);
        #pragma unroll
        for (int r = 0; r < 4; ++r)
            if (acc[r] > best[r]) { best[r] = acc[r]; bid[r] = t; }
    }

    // cross-lane argmax over the 16 code-cols; tie -> smaller code index
    #pragma unroll
    for (int r = 0; r < 4; ++r) {
        float s = best[r];
        int   c = bid[r] * 16 + col;
        #pragma unroll
        for (int mk = 1; mk < 16; mk <<= 1) {
            float os = __shfl_xor(s, mk);
            int   oc = __shfl_xor(c, mk);
            if (os > s || (os == s && oc < c)) { s = os; c = oc; }
        }
        if (col == 0) idx_lds[w * 16 + grp * 4 + r] = c;
    }
    __syncthreads();

    // epilogue: write q (exact fp32 from codebook) + exact fp32 loss
    float ls = 0.f;
    const int qi = idx_lds[w * 16 + col];
    const float* qp = cb + qi * DIM + grp * 8;
    float* ob = out + 1 + (size_t)b * CHW + hwp;
    #pragma unroll
    for (int h = 0; h < 2; ++h) {
        float4 qa = *(const float4*)(qp + h * 32);
        float4 qb = *(const float4*)(qp + h * 32 + 4);
        float q[8] = {qa.x, qa.y, qa.z, qa.w, qb.x, qb.y, qb.z, qb.w};
        #pragma unroll
        for (int j = 0; j < 8; ++j) {
            float d = zf[h][j] - q[j];
            ls = fmaf(d, d, ls);
            ob[(h * 32 + grp * 8 + j) * HW] = q[j];
        }
    }

    #pragma unroll
    for (int off = 32; off; off >>= 1) ls += __shfl_down(ls, off);
    if (lane == 0) red[w] = ls;
    __syncthreads();
    if (tid == 0) {
        float s = 0.f;
        #pragma unroll
        for (int i = 0; i < 8; ++i) s += red[i];
        atomicAdd(out, s * (1.25f / (float)(NPIX * DIM)));
    }
}

extern "C" void kernel_launch(void* const* d_in, const int* in_sizes, int n_in,
                              void* d_out, int out_size, void* d_ws, size_t ws_size,
                              hipStream_t stream) {
    const float* z  = (const float*)d_in[0];   // (32,64,64,64) f32
    const float* cb = (const float*)d_in[1];   // (512,64) f32
    float* out = (float*)d_out;                // [loss | zq]
    float* ws  = (float*)d_ws;
    float* cnh  = ws;                          // 512 f32
    uint4* frag = (uint4*)(ws + 512);          // 64 KB bf16 fragments

    vq_prep<<<8, 512, 0, stream>>>(cb, cnh, frag, out);
    vq_main<<<1024, 512, 0, stream>>>(z, cb, cnh, frag, out);
}

// Round 5
// 37.049 us; speedup vs baseline: 1.3808x; 1.3808x over previous
//
#include <hip/hip_runtime.h>

#define N_E   512
#define DIM   64
#define HW    4096        // 64*64
#define CHW   (64*HW)     // 262144
#define NPIX  131072      // 32*64*64
#define QS    258         // q-tile px stride (floats): 2-way bank alias (free), 8B-aligned

typedef __attribute__((ext_vector_type(8))) short  short8;   // 8 bf16 (4 VGPRs)
typedef __attribute__((ext_vector_type(4))) float  f32x4;

__device__ __forceinline__ unsigned short f2bf(float x) {
    unsigned u = __builtin_bit_cast(unsigned, x);
    return (unsigned short)((u + 0x7FFFu + ((u >> 16) & 1u)) >> 16);   // RNE
}

// --- prep: pack codebook into bf16 B-fragments + norms + zero loss slot ------
// frag[g], g = tile*128 + h*64 + lane : 8 bf16 = cb[tile*16+(lane&15)][h*32+(lane>>4)*8 + j]
__global__ __launch_bounds__(512) void vq_prep(
        const float* __restrict__ cb, float* __restrict__ cnh,
        uint4* __restrict__ frag, float* __restrict__ out) {
    int g    = blockIdx.x * 512 + threadIdx.x;   // 0..4095
    int tile = g >> 7;
    int h    = (g >> 6) & 1;
    int ln   = g & 63;
    const float* src = cb + (tile * 16 + (ln & 15)) * DIM + h * 32 + (ln >> 4) * 8;
    float4 a = *(const float4*)src;
    float4 b = *(const float4*)(src + 4);
    uint4 o;
    o.x = (unsigned)f2bf(a.x) | ((unsigned)f2bf(a.y) << 16);
    o.y = (unsigned)f2bf(a.z) | ((unsigned)f2bf(a.w) << 16);
    o.z = (unsigned)f2bf(b.x) | ((unsigned)f2bf(b.y) << 16);
    o.w = (unsigned)f2bf(b.z) | ((unsigned)f2bf(b.w) << 16);
    frag[g] = o;
    if (blockIdx.x == 0) {
        const float4* c = (const float4*)(cb + threadIdx.x * DIM);
        float s = 0.f;
        #pragma unroll
        for (int k = 0; k < DIM / 4; ++k) {
            float4 v = c[k];
            s += v.x * v.x + v.y * v.y + v.z * v.z + v.w * v.w;
        }
        cnh[threadIdx.x] = -0.5f * s;
        if (threadIdx.x == 0) out[0] = 0.f;
    }
}

// --- main: LDS codebook (pre-packed, linear copy) + MFMA + LDS-transposed store
__global__ __launch_bounds__(512, 4) void vq_main(
        const float* __restrict__ z, const float* __restrict__ cb,
        const float* __restrict__ cnh, const uint4* __restrict__ frag,
        float* __restrict__ out) {
    // union: phase A = 64KB bf16 B-fragments; phase B = q-tile [64][QS] fp32
    __shared__ __align__(16) float smem[DIM * QS];   // 66048 B
    __shared__ float cn[N_E];
    __shared__ int   idx_lds[256];
    __shared__ float red[8];

    const int tid  = threadIdx.x;
    const int w    = tid >> 6;
    const int lane = tid & 63;
    const int col  = lane & 15;
    const int grp  = lane >> 4;

    const int pbase = blockIdx.x * 256;        // 256 pixels/block (32/wave)
    const int b     = pbase >> 12;
    const int hwb   = pbase & 4095;
    const int hwp   = hwb + w * 32 + col;      // + m*16
    const float* zp = z + (size_t)b * CHW + hwp;

    // stage pre-packed codebook -> LDS (linear, fully coalesced)
    uint4* Blds = (uint4*)smem;
    #pragma unroll
    for (int i = 0; i < 8; ++i) Blds[tid + i * 512] = frag[tid + i * 512];
    cn[tid] = cnh[tid];

    // z loads (fp32 kept for exact loss) — independent, overlap the LDS fill
    float zf[2][2][8];
    #pragma unroll
    for (int m = 0; m < 2; ++m)
        #pragma unroll
        for (int h = 0; h < 2; ++h)
            #pragma unroll
            for (int j = 0; j < 8; ++j)
                zf[m][h][j] = zp[m * 16 + (h * 32 + grp * 8 + j) * HW];

    short8 afr[2][2];
    #pragma unroll
    for (int m = 0; m < 2; ++m)
        #pragma unroll
        for (int h = 0; h < 2; ++h)
            #pragma unroll
            for (int j = 0; j < 8; ++j)
                afr[m][h][j] = (short)f2bf(zf[m][h][j]);

    __syncthreads();

    // MFMA score loop: argmax of (z.c - 0.5||c||^2) == argmin distance
    float best[2][4];
    int   bid[2][4];
    #pragma unroll
    for (int m = 0; m < 2; ++m)
        #pragma unroll
        for (int r = 0; r < 4; ++r) { best[m][r] = -1e30f; bid[m][r] = 0; }

    const short8* B8 = (const short8*)smem;
    #pragma unroll 2
    for (int t = 0; t < 32; ++t) {
        short8 b0 = B8[t * 128 + lane];
        short8 b1 = B8[t * 128 + 64 + lane];
        const float c0 = cn[t * 16 + col];
        f32x4 a0 = {c0, c0, c0, c0};
        f32x4 a1 = {c0, c0, c0, c0};
        a0 = __builtin_amdgcn_mfma_f32_16x16x32_bf16(afr[0][0], b0, a0, 0, 0, 0);
        a0 = __builtin_amdgcn_mfma_f32_16x16x32_bf16(afr[0][1], b1, a0, 0, 0, 0);
        a1 = __builtin_amdgcn_mfma_f32_16x16x32_bf16(afr[1][0], b0, a1, 0, 0, 0);
        a1 = __builtin_amdgcn_mfma_f32_16x16x32_bf16(afr[1][1], b1, a1, 0, 0, 0);
        #pragma unroll
        for (int r = 0; r < 4; ++r) {
            if (a0[r] > best[0][r]) { best[0][r] = a0[r]; bid[0][r] = t; }
            if (a1[r] > best[1][r]) { best[1][r] = a1[r]; bid[1][r] = t; }
        }
    }

    // cross-lane argmax over 16 code-cols; tie -> smaller code index
    #pragma unroll
    for (int m = 0; m < 2; ++m)
        #pragma unroll
        for (int r = 0; r < 4; ++r) {
            float s = best[m][r];
            int   c = bid[m][r] * 16 + col;
            #pragma unroll
            for (int mk = 1; mk < 16; mk <<= 1) {
                float os = __shfl_xor(s, mk);
                int   oc = __shfl_xor(c, mk);
                if (os > s || (os == s && oc < c)) { s = os; c = oc; }
            }
            if (col == 0) idx_lds[w * 32 + m * 16 + grp * 4 + r] = c;
        }
    __syncthreads();   // idx ready; all waves done reading Blds -> reuse as q-tile

    // phase 1: gather q rows (fp32, L2), exact loss, scatter q into LDS tile
    float ls = 0.f;
    #pragma unroll
    for (int m = 0; m < 2; ++m) {
        const int qi = idx_lds[w * 32 + m * 16 + col];
        const float* qp = cb + qi * DIM + grp * 8;
        const int px = w * 32 + m * 16 + col;
        #pragma unroll
        for (int h = 0; h < 2; ++h) {
            float4 qa = *(const float4*)(qp + h * 32);
            float4 qb = *(const float4*)(qp + h * 32 + 4);
            float q[8] = {qa.x, qa.y, qa.z, qa.w, qb.x, qb.y, qb.z, qb.w};
            #pragma unroll
            for (int j = 0; j < 8; ++j) {
                float d = zf[m][h][j] - q[j];
                ls = fmaf(d, d, ls);
                smem[(h * 32 + grp * 8 + j) * QS + px] = q[j];
            }
        }
    }

    #pragma unroll
    for (int off = 32; off; off >>= 1) ls += __shfl_down(ls, off);
    if (lane == 0) red[w] = ls;
    __syncthreads();   // q-tile complete (also covers red[])

    // phase 2: coalesced store — 256 B contiguous per wave-instruction
    float* ob = out + 1 + (size_t)b * CHW + hwb;
    #pragma unroll
    for (int it = 0; it < 32; ++it) {
        int e = it * 512 + tid;
        int c = e >> 8;        // channel 0..63
        int p = e & 255;       // pixel within block tile
        ob[c * HW + p] = smem[c * QS + p];
    }

    if (tid == 0) {
        float s = 0.f;
        #pragma unroll
        for (int i = 0; i < 8; ++i) s += red[i];
        atomicAdd(out, s * (1.25f / (float)(NPIX * DIM)));
    }
}

extern "C" void kernel_launch(void* const* d_in, const int* in_sizes, int n_in,
                              void* d_out, int out_size, void* d_ws, size_t ws_size,
                              hipStream_t stream) {
    const float* z  = (const float*)d_in[0];   // (32,64,64,64) f32
    const float* cb = (const float*)d_in[1];   // (512,64) f32
    float* out = (float*)d_out;                // [loss | zq]
    float* ws  = (float*)d_ws;
    float* cnh  = ws;                          // 512 f32
    uint4* frag = (uint4*)(ws + 512);          // 64 KB bf16 fragments

    vq_prep<<<8, 512, 0, stream>>>(cb, cnh, frag, out);
    vq_main<<<512, 512, 0, stream>>>(z, cb, cnh, frag, out);
}